// Round 6
// baseline (838.106 us; speedup 1.0000x reference)
//
#include <hip/hip_runtime.h>
#include <hip/hip_fp16.h>
#include <math.h>

#define HDIM 128
#define DP   64    // denom privatization blocks
#define NB   64    // nodes per aggregation bucket (j >> 6)
#define CAP  1536  // edge slots per bucket (mean 1024, sd ~32 -> 16 sigma)
#define BINB 64    // binning blocks

typedef __attribute__((ext_vector_type(8))) short short8;   // 8 bf16
typedef __attribute__((ext_vector_type(4))) float f32x4;

// ---- helpers ----------------------------------------------------------------
__device__ __forceinline__ float gelu_f(float v) {
    return 0.5f * v * (1.0f + erff(v * 0.70710678118654752440f));
}
// f32 -> bf16 (round-to-nearest-even), result in low 16 bits
__device__ __forceinline__ unsigned bf_rne(float f) {
    unsigned u = __float_as_uint(f);
    return (u + 0x7fffu + ((u >> 16) & 1u)) >> 16;
}
__device__ __forceinline__ float bf_lo(unsigned u) {
    return __uint_as_float(u << 16);
}
__device__ __forceinline__ float bf_hi(unsigned u) {
    return __uint_as_float(u & 0xffff0000u);
}

// ---- kernel 1: scores si = x.a_i, sj = x.a_j; x -> paired-packed bf16 -------
// Paired packing: word w of a row = (col w, col w+64) as 2 bf16. The wave
// already holds exactly that pair (xa, xb) per lane.
__global__ void __launch_bounds__(256) k_scores(
    const float* __restrict__ x, const float* __restrict__ a_i,
    const float* __restrict__ a_j, float* __restrict__ si,
    float* __restrict__ sj, unsigned* __restrict__ xbp,
    unsigned* __restrict__ gcnt, int N) {
    if (blockIdx.x == 0)
        for (int w = threadIdx.x; w < 1024; w += 256) gcnt[w] = 0u;
    const int wave = threadIdx.x >> 6;
    const int lane = threadIdx.x & 63;
    const int n = blockIdx.x * 4 + wave;
    if (n >= N) return;
    const float xa = x[(size_t)n * HDIM + lane];
    const float xb = x[(size_t)n * HDIM + 64 + lane];
    xbp[(size_t)n * 64 + lane] = bf_rne(xa) | (bf_rne(xb) << 16);
    float vi = xa * a_i[lane] + xb * a_i[64 + lane];
    float vj = xa * a_j[lane] + xb * a_j[64 + lane];
    #pragma unroll
    for (int d = 32; d; d >>= 1) {
        vi += __shfl_xor(vi, d, 64);
        vj += __shfl_xor(vj, d, 64);
    }
    if (lane == 0) {
        si[n] = vi;
        sj[n] = vj;
    }
}

// ---- kernel 2: denom segment-sum over idx_i via LDS privatization -----------
// DP persistent blocks, 4 node-quarter passes (50 KB LDS each). Pass 0 also
// computes ex = exp(leaky_relu(si[i]+sj[j])) and stores fp16 exbuf.
// exp(e)/sum == softmax since |e| <= ~10 (no overflow) -> no segment-max pass.
__global__ void __launch_bounds__(1024) k_den(
    const int* __restrict__ idx_i, const int* __restrict__ idx_j,
    const float* __restrict__ si, const float* __restrict__ sj,
    unsigned short* __restrict__ exbuf, float* __restrict__ denp,
    int N, int E_) {
    __shared__ float den_l[12544];          // 50176 B
    const int b = blockIdx.x;
    const int chunk = (E_ + DP - 1) / DP;
    const int e0 = b * chunk;
    const int e1 = min(e0 + chunk, E_);
    const int Q = (N + 3) >> 2;             // 12500
    for (int pass = 0; pass < 4; ++pass) {
        const int lo = pass * Q;
        for (int w = threadIdx.x; w < Q; w += 1024) den_l[w] = 0.f;
        __syncthreads();
        for (int t = e0 + threadIdx.x; t < e1; t += 1024) {
            const int i = idx_i[t];
            float ex;
            if (pass == 0) {
                const int j = idx_j[t];
                float e = si[i] + sj[j];
                e = (e > 0.f) ? e : 0.01f * e;   // leaky_relu slope 0.01
                ex = __expf(e);
                exbuf[t] = __half_as_ushort(__float2half(ex));
            } else {
                ex = __half2float(__ushort_as_half(exbuf[t]));
            }
            const unsigned rel = (unsigned)(i - lo);
            if (rel < (unsigned)Q) atomicAdd(&den_l[rel], ex);
        }
        __syncthreads();
        for (int w = threadIdx.x; w < Q && lo + w < N; w += 1024)
            denp[(size_t)b * N + lo + w] = den_l[w];
        __syncthreads();
    }
}

// ---- kernel 3: column-reduce denom partials ---------------------------------
__global__ void __launch_bounds__(256) k_denred(const float* __restrict__ denp,
                                                float* __restrict__ denom,
                                                int N) {
    const int v = blockIdx.x * 256 + threadIdx.x;
    if (v >= N) return;
    float s = 0.f;
    for (int b = 0; b < DP; ++b) s += denp[(size_t)b * N + v];
    denom[v] = s;
}

// ---- kernel 4: group edges by 64-node destination bucket --------------------
// 2 passes per chunk: LDS histogram -> one global atomic per (block,bucket)
// reserves space (~50k atomics total) -> LDS-cursor scatter. Record packs
// (i | jrel<<24, f32 ex). No per-node atomics anywhere.
__global__ void __launch_bounds__(1024) k_bin(
    const int* __restrict__ idx_i, const int* __restrict__ idx_j,
    const unsigned short* __restrict__ exbuf, unsigned* __restrict__ gcnt,
    uint2* __restrict__ edges, int nbuk, int E_) {
    __shared__ unsigned cnt_l[1024];
    const int blk = blockIdx.x;
    const int chunk = (E_ + BINB - 1) / BINB;
    const int e0 = blk * chunk;
    const int e1 = min(e0 + chunk, E_);
    for (int w = threadIdx.x; w < nbuk; w += 1024) cnt_l[w] = 0u;
    __syncthreads();
    for (int t = e0 + threadIdx.x; t < e1; t += 1024)
        atomicAdd(&cnt_l[idx_j[t] >> 6], 1u);
    __syncthreads();
    for (int w = threadIdx.x; w < nbuk; w += 1024)
        cnt_l[w] = atomicAdd(&gcnt[w], cnt_l[w]);   // own slot RMW: no hazard
    __syncthreads();
    for (int t = e0 + threadIdx.x; t < e1; t += 1024) {
        const int j = idx_j[t];
        const int b = j >> 6;
        const unsigned slot = min(atomicAdd(&cnt_l[b], 1u), (unsigned)(CAP - 1));
        const float ex = __half2float(__ushort_as_half(exbuf[t]));
        edges[(size_t)b * CAP + slot] = make_uint2(
            (unsigned)idx_i[t] | ((unsigned)(j & 63) << 24),
            __float_as_uint(ex));
    }
}

// ---- kernel 5: m' = (x + x @ W)/denom via bf16 MFMA, paired-packed output ---
// W staged in LDS paired-packed transposed: wl[n][w] = (W[w][n], W[w+64][n]).
// MFMA 16x16x32; the k-order fed to A and B is the same custom permutation
// (pairs (k, k+64) interleaved), which is valid since contraction order is
// immaterial as long as A and B agree.
__global__ void __launch_bounds__(256) k_gemm(
    const unsigned* __restrict__ xbp, const float* __restrict__ Wm,
    const float* __restrict__ denom, unsigned* __restrict__ mbp, int N) {
    __shared__ unsigned wl[128][68];   // +4 pad: 16B-aligned rows, 2-way banks
    const int t = threadIdx.x;
    {
        const int n = t & 127;
        const int h = t >> 7;
        for (int w = h * 32; w < h * 32 + 32; ++w) {
            const float f0 = Wm[w * 128 + n];
            const float f1 = Wm[(w + 64) * 128 + n];
            wl[n][w] = bf_rne(f0) | (bf_rne(f1) << 16);
        }
    }
    __syncthreads();
    const int wave = t >> 6;
    const int lane = t & 63;
    const int q = lane >> 4;
    const int m16 = lane & 15;
    for (int rb = blockIdx.x * 64; rb < N; rb += 256 * 64) {
        const int r0 = rb + wave * 16;
        if (r0 >= N) continue;
        const int rowA = min(r0 + m16, N - 1);
        union { uint4 u; short8 s; } a[4];
        #pragma unroll
        for (int kb = 0; kb < 4; ++kb)
            a[kb].u = *(const uint4*)(xbp + (size_t)rowA * 64 + kb * 16 + q * 4);
        f32x4 acc[8];
        #pragma unroll
        for (int c = 0; c < 8; ++c) acc[c] = (f32x4){0.f, 0.f, 0.f, 0.f};
        #pragma unroll
        for (int kb = 0; kb < 4; ++kb) {
            #pragma unroll
            for (int c = 0; c < 8; ++c) {
                const short8 bfr =
                    *(const short8*)&wl[c * 16 + m16][kb * 16 + q * 4];
                acc[c] = __builtin_amdgcn_mfma_f32_16x16x32_bf16(
                    a[kb].s, bfr, acc[c], 0, 0, 0);
            }
        }
        #pragma unroll
        for (int r = 0; r < 4; ++r) {
            const int row = r0 + q * 4 + r;   // C/D: row = quad*4+reg
            if (row >= N) continue;
            const float rdv = 1.0f / denom[row];  // denom==0 rows never read
            #pragma unroll
            for (int c = 0; c < 4; ++c) {
                const int w = m16 + 16 * c;       // C/D: col = lane&15 (+16c)
                const unsigned xv = xbp[(size_t)row * 64 + w];
                const float vlo = (bf_lo(xv) + acc[c][r]) * rdv;
                const float vhi = (bf_hi(xv) + acc[c + 4][r]) * rdv;
                mbp[(size_t)row * 64 + w] = bf_rne(vlo) | (bf_rne(vhi) << 16);
            }
        }
    }
}

// ---- kernel 6: bucket aggregation in LDS out-tile + fused exact GELU --------
// Block b owns nodes [b*64, b*64+64). Wave-per-edge: broadcast record,
// coalesced 256B gather of m'[i], 2 ds_add_f32 per lane into the tile
// (word = jrel*128 + lane / +64: bank stride 1, conflict-free).
__global__ void __launch_bounds__(1024) k_agg(
    const unsigned* __restrict__ gcnt, const uint2* __restrict__ edges,
    const unsigned* __restrict__ mbp, float* __restrict__ out, int N) {
    __shared__ float outl[NB * HDIM];   // 32 KB
    const int b = blockIdx.x;
    for (int w = threadIdx.x; w < NB * HDIM; w += 1024) outl[w] = 0.f;
    __syncthreads();
    const int cntb = min((int)gcnt[b], CAP);
    const uint2* eb = edges + (size_t)b * CAP;
    const int wave = threadIdx.x >> 6;
    const int lane = threadIdx.x & 63;
    for (int p = wave * 4; p < cntb; p += 64) {   // 4 indep gathers in flight
        const int k1 = (p + 1 < cntb), k2 = (p + 2 < cntb), k3 = (p + 3 < cntb);
        uint2 r0 = eb[p];
        uint2 r1 = k1 ? eb[p + 1] : r0;
        uint2 r2 = k2 ? eb[p + 2] : r0;
        uint2 r3 = k3 ? eb[p + 3] : r0;
        const unsigned u0 = mbp[(size_t)(r0.x & 0xffffffu) * 64 + lane];
        const unsigned u1 = k1 ? mbp[(size_t)(r1.x & 0xffffffu) * 64 + lane] : 0u;
        const unsigned u2 = k2 ? mbp[(size_t)(r2.x & 0xffffffu) * 64 + lane] : 0u;
        const unsigned u3 = k3 ? mbp[(size_t)(r3.x & 0xffffffu) * 64 + lane] : 0u;
        {
            const float a0 = __uint_as_float(r0.y);
            const int j0 = (int)(r0.x >> 24) * HDIM;
            atomicAdd(&outl[j0 + lane], a0 * bf_lo(u0));
            atomicAdd(&outl[j0 + 64 + lane], a0 * bf_hi(u0));
        }
        if (k1) {
            const float a1 = __uint_as_float(r1.y);
            const int j1 = (int)(r1.x >> 24) * HDIM;
            atomicAdd(&outl[j1 + lane], a1 * bf_lo(u1));
            atomicAdd(&outl[j1 + 64 + lane], a1 * bf_hi(u1));
        }
        if (k2) {
            const float a2 = __uint_as_float(r2.y);
            const int j2 = (int)(r2.x >> 24) * HDIM;
            atomicAdd(&outl[j2 + lane], a2 * bf_lo(u2));
            atomicAdd(&outl[j2 + 64 + lane], a2 * bf_hi(u2));
        }
        if (k3) {
            const float a3 = __uint_as_float(r3.y);
            const int j3 = (int)(r3.x >> 24) * HDIM;
            atomicAdd(&outl[j3 + lane], a3 * bf_lo(u3));
            atomicAdd(&outl[j3 + 64 + lane], a3 * bf_hi(u3));
        }
    }
    __syncthreads();
    const int nb0 = b << 6;
    for (int idx = threadIdx.x; idx < NB * HDIM; idx += 1024) {
        const int n = nb0 + (idx >> 7);
        if (n < N) out[(size_t)n * HDIM + (idx & 127)] = gelu_f(outl[idx]);
    }
}

// ---- launcher ---------------------------------------------------------------
extern "C" void kernel_launch(void* const* d_in, const int* in_sizes, int n_in,
                              void* d_out, int out_size, void* d_ws,
                              size_t ws_size, hipStream_t stream) {
    const float* x   = (const float*)d_in[0];
    const int*   eix = (const int*)d_in[1];
    const float* a_i = (const float*)d_in[2];
    const float* a_j = (const float*)d_in[3];
    const float* Wm  = (const float*)d_in[4];
    float* out = (float*)d_out;

    const int N = in_sizes[0] / HDIM;  // 50000
    const int E = in_sizes[1] / 2;     // 800000
    const int nbuk = (N + NB - 1) / NB;  // 782

    // workspace layout (~50 MB, all sections 16B-aligned)
    unsigned* xbp  = (unsigned*)d_ws;                     // N*64 (12.8 MB)
    unsigned* mbp  = xbp + (size_t)N * 64;                // N*64 (12.8 MB)
    float* denp    = (float*)(mbp + (size_t)N * 64);      // DP*N (12.8 MB)
    float* si      = denp + (size_t)DP * N;               // N
    float* sj      = si + N;                              // N
    float* denom   = sj + N;                              // N
    unsigned* gcnt = (unsigned*)(denom + N);              // 1024
    unsigned short* exbuf = (unsigned short*)(gcnt + 1024);  // E (1.6 MB)
    uint2* edges   = (uint2*)(exbuf + E);                 // nbuk*CAP (9.6 MB)

    const int* idx_j = eix;       // edge_index[0]: output node
    const int* idx_i = eix + E;   // edge_index[1]: source / softmax segment

    k_scores<<<(N + 3) / 4, 256, 0, stream>>>(x, a_i, a_j, si, sj, xbp, gcnt,
                                              N);
    k_den<<<DP, 1024, 0, stream>>>(idx_i, idx_j, si, sj, exbuf, denp, N, E);
    k_denred<<<(N + 255) / 256, 256, 0, stream>>>(denp, denom, N);
    k_bin<<<BINB, 1024, 0, stream>>>(idx_i, idx_j, exbuf, gcnt, edges, nbuk,
                                     E);
    k_gemm<<<256, 256, 0, stream>>>(xbp, Wm, denom, mbp, N);
    k_agg<<<nbuk, 1024, 0, stream>>>(gcnt, edges, mbp, out, N);
}

// Round 7
// 185.481 us; speedup vs baseline: 4.5185x; 4.5185x over previous
//
#include <hip/hip_runtime.h>
#include <hip/hip_fp16.h>
#include <math.h>

#define HDIM 128
#define DP   256   // denom privatization blocks
#define NB   64    // nodes per aggregation bucket (j >> 6)
#define CAP  1536  // edge slots per bucket (mean 1024, sd ~32 -> 16 sigma)
#define BINB 128   // binning blocks

typedef __attribute__((ext_vector_type(8))) short short8;   // 8 bf16
typedef __attribute__((ext_vector_type(4))) float f32x4;

// ---- helpers ----------------------------------------------------------------
__device__ __forceinline__ float gelu_f(float v) {
    return 0.5f * v * (1.0f + erff(v * 0.70710678118654752440f));
}
// f32 -> bf16 (round-to-nearest-even), result in low 16 bits
__device__ __forceinline__ unsigned bf_rne(float f) {
    unsigned u = __float_as_uint(f);
    return (u + 0x7fffu + ((u >> 16) & 1u)) >> 16;
}
__device__ __forceinline__ float bf_lo(unsigned u) {
    return __uint_as_float(u << 16);
}
__device__ __forceinline__ float bf_hi(unsigned u) {
    return __uint_as_float(u & 0xffff0000u);
}

// ---- kernel 1: scores si = x.a_i, sj = x.a_j; x -> paired-packed bf16 -------
// Paired packing: word w of a row = (col w, col w+64) as 2 bf16.
__global__ void __launch_bounds__(256) k_scores(
    const float* __restrict__ x, const float* __restrict__ a_i,
    const float* __restrict__ a_j, float* __restrict__ si,
    float* __restrict__ sj, unsigned* __restrict__ xbp,
    unsigned* __restrict__ gcnt, int N) {
    if (blockIdx.x == 0)
        for (int w = threadIdx.x; w < 1024; w += 256) gcnt[w] = 0u;
    const int wave = threadIdx.x >> 6;
    const int lane = threadIdx.x & 63;
    const int n = blockIdx.x * 4 + wave;
    if (n >= N) return;
    const float xa = x[(size_t)n * HDIM + lane];
    const float xb = x[(size_t)n * HDIM + 64 + lane];
    xbp[(size_t)n * 64 + lane] = bf_rne(xa) | (bf_rne(xb) << 16);
    float vi = xa * a_i[lane] + xb * a_i[64 + lane];
    float vj = xa * a_j[lane] + xb * a_j[64 + lane];
    #pragma unroll
    for (int d = 32; d; d >>= 1) {
        vi += __shfl_xor(vi, d, 64);
        vj += __shfl_xor(vj, d, 64);
    }
    if (lane == 0) {
        si[n] = vi;
        sj[n] = vj;
    }
}

// ---- kernel 2: denom segment-sum over idx_i via LDS privatization -----------
// DP persistent blocks, 4 node-quarter passes (50 KB LDS each). Pass 0 also
// computes ex = exp(leaky_relu(si[i]+sj[j])) and stores fp16 exbuf.
// exp(e)/sum == softmax since |e| <= ~10 (no overflow) -> no segment-max pass.
// LDS atomic budget: 3125 lane-ops/block total — well under the serialization
// cliff (R6: 102M lane-ops = 680us; ~4cyc per lane-op).
__global__ void __launch_bounds__(1024) k_den(
    const int* __restrict__ idx_i, const int* __restrict__ idx_j,
    const float* __restrict__ si, const float* __restrict__ sj,
    unsigned short* __restrict__ exbuf, float* __restrict__ denp,
    int N, int E_) {
    __shared__ float den_l[12544];          // 50176 B
    const int b = blockIdx.x;
    const int chunk = (E_ + DP - 1) / DP;
    const int e0 = b * chunk;
    const int e1 = min(e0 + chunk, E_);
    const int Q = (N + 3) >> 2;             // 12500
    for (int pass = 0; pass < 4; ++pass) {
        const int lo = pass * Q;
        for (int w = threadIdx.x; w < Q; w += 1024) den_l[w] = 0.f;
        __syncthreads();
        for (int t = e0 + threadIdx.x; t < e1; t += 1024) {
            const int i = idx_i[t];
            float ex;
            if (pass == 0) {
                const int j = idx_j[t];
                float e = si[i] + sj[j];
                e = (e > 0.f) ? e : 0.01f * e;   // leaky_relu slope 0.01
                ex = __expf(e);
                exbuf[t] = __half_as_ushort(__float2half(ex));
            } else {
                ex = __half2float(__ushort_as_half(exbuf[t]));
            }
            const unsigned rel = (unsigned)(i - lo);
            if (rel < (unsigned)Q) atomicAdd(&den_l[rel], ex);
        }
        __syncthreads();
        for (int w = threadIdx.x; w < Q && lo + w < N; w += 1024)
            denp[(size_t)b * N + lo + w] = den_l[w];
        __syncthreads();
    }
}

// ---- kernel 3: column-reduce denom partials ---------------------------------
__global__ void __launch_bounds__(256) k_denred(const float* __restrict__ denp,
                                                float* __restrict__ denom,
                                                int N) {
    const int v = blockIdx.x * 256 + threadIdx.x;
    if (v >= N) return;
    float s = 0.f;
    for (int b = 0; b < DP; ++b) s += denp[(size_t)b * N + v];
    denom[v] = s;
}

// ---- kernel 4: group edges by 64-node destination bucket --------------------
// 2 passes per chunk: LDS histogram -> one global atomic per (block,bucket)
// reserves space (~100k atomics total) -> LDS-cursor scatter. Record packs
// (i | jrel<<24, f32 ex).
__global__ void __launch_bounds__(1024) k_bin(
    const int* __restrict__ idx_i, const int* __restrict__ idx_j,
    const unsigned short* __restrict__ exbuf, unsigned* __restrict__ gcnt,
    uint2* __restrict__ edges, int nbuk, int E_) {
    __shared__ unsigned cnt_l[1024];
    const int blk = blockIdx.x;
    const int chunk = (E_ + BINB - 1) / BINB;
    const int e0 = blk * chunk;
    const int e1 = min(e0 + chunk, E_);
    for (int w = threadIdx.x; w < nbuk; w += 1024) cnt_l[w] = 0u;
    __syncthreads();
    for (int t = e0 + threadIdx.x; t < e1; t += 1024)
        atomicAdd(&cnt_l[idx_j[t] >> 6], 1u);
    __syncthreads();
    for (int w = threadIdx.x; w < nbuk; w += 1024)
        cnt_l[w] = atomicAdd(&gcnt[w], cnt_l[w]);   // own slot RMW: no hazard
    __syncthreads();
    for (int t = e0 + threadIdx.x; t < e1; t += 1024) {
        const int j = idx_j[t];
        const int b = j >> 6;
        const unsigned slot = min(atomicAdd(&cnt_l[b], 1u), (unsigned)(CAP - 1));
        const float ex = __half2float(__ushort_as_half(exbuf[t]));
        edges[(size_t)b * CAP + slot] = make_uint2(
            (unsigned)idx_i[t] | ((unsigned)(j & 63) << 24),
            __float_as_uint(ex));
    }
}

// ---- kernel 5: m' = (x + x @ W)/denom via bf16 MFMA, paired-packed output ---
// (verified correct in R6: feeds every output, absmax unchanged)
__global__ void __launch_bounds__(256) k_gemm(
    const unsigned* __restrict__ xbp, const float* __restrict__ Wm,
    const float* __restrict__ denom, unsigned* __restrict__ mbp, int N) {
    __shared__ unsigned wl[128][68];   // +4 pad: 16B-aligned rows
    const int t = threadIdx.x;
    {
        const int n = t & 127;
        const int h = t >> 7;
        for (int w = h * 32; w < h * 32 + 32; ++w) {
            const float f0 = Wm[w * 128 + n];
            const float f1 = Wm[(w + 64) * 128 + n];
            wl[n][w] = bf_rne(f0) | (bf_rne(f1) << 16);
        }
    }
    __syncthreads();
    const int wave = t >> 6;
    const int lane = t & 63;
    const int q = lane >> 4;
    const int m16 = lane & 15;
    const int r0 = blockIdx.x * 64 + wave * 16;
    if (r0 >= N) return;
    const int rowA = min(r0 + m16, N - 1);
    union { uint4 u; short8 s; } a[4];
    #pragma unroll
    for (int kb = 0; kb < 4; ++kb)
        a[kb].u = *(const uint4*)(xbp + (size_t)rowA * 64 + kb * 16 + q * 4);
    f32x4 acc[8];
    #pragma unroll
    for (int c = 0; c < 8; ++c) acc[c] = (f32x4){0.f, 0.f, 0.f, 0.f};
    #pragma unroll
    for (int kb = 0; kb < 4; ++kb) {
        #pragma unroll
        for (int c = 0; c < 8; ++c) {
            const short8 bfr =
                *(const short8*)&wl[c * 16 + m16][kb * 16 + q * 4];
            acc[c] = __builtin_amdgcn_mfma_f32_16x16x32_bf16(
                a[kb].s, bfr, acc[c], 0, 0, 0);
        }
    }
    #pragma unroll
    for (int r = 0; r < 4; ++r) {
        const int row = r0 + q * 4 + r;   // C/D: row = quad*4+reg
        if (row >= N) continue;
        const float rdv = 1.0f / denom[row];  // denom==0 rows never read
        #pragma unroll
        for (int c = 0; c < 4; ++c) {
            const int w = m16 + 16 * c;       // C/D: col = lane&15 (+16c)
            const unsigned xv = xbp[(size_t)row * 64 + w];
            const float vlo = (bf_lo(xv) + acc[c][r]) * rdv;
            const float vhi = (bf_hi(xv) + acc[c + 4][r]) * rdv;
            mbp[(size_t)row * 64 + w] = bf_rne(vlo) | (bf_rne(vhi) << 16);
        }
    }
}

// ---- kernel 6: bucket aggregation: local per-node CSR in LDS, then ----------
// wave-per-node REGISTER accumulation (no atomics in the hot loop).
// LDS atomic budget: ~1536 u32 rank-grabs per block — negligible.
__global__ void __launch_bounds__(1024) k_agg(
    const unsigned* __restrict__ gcnt, const uint2* __restrict__ edges,
    const unsigned* __restrict__ mbp, float* __restrict__ out, int N) {
    __shared__ uint2 srec[CAP];            // 12 KB sorted records
    __shared__ unsigned cnt_l[NB];
    __shared__ unsigned off_l[NB];
    const int b = blockIdx.x;
    const int cntb = min((int)gcnt[b], CAP);
    const uint2* eb = edges + (size_t)b * CAP;
    if (threadIdx.x < NB) cnt_l[threadIdx.x] = 0u;
    __syncthreads();
    // phase A: load records, grab per-node rank (<=2 edges per thread)
    uint2 rloc[2];
    int jloc[2], kloc[2], nmine = 0;
    for (int t = threadIdx.x; t < cntb; t += 1024) {
        const uint2 rec = eb[t];
        const int jrel = (int)(rec.x >> 24);
        const int rank = (int)atomicAdd(&cnt_l[jrel], 1u);
        rloc[nmine] = rec;
        jloc[nmine] = jrel;
        kloc[nmine] = rank;
        ++nmine;
    }
    __syncthreads();
    // phase B: exclusive scan of the 64 counters (first wave, shuffle scan)
    if (threadIdx.x < 64) {
        const unsigned v = cnt_l[threadIdx.x];
        unsigned s = v;
        #pragma unroll
        for (int d = 1; d < 64; d <<= 1) {
            const unsigned o = __shfl_up(s, d, 64);
            if ((int)threadIdx.x >= d) s += o;
        }
        off_l[threadIdx.x] = s - v;   // exclusive prefix
    }
    __syncthreads();
    // phase C: scatter into sorted LDS array
    for (int k = 0; k < nmine; ++k)
        srec[off_l[jloc[k]] + kloc[k]] = rloc[k];
    __syncthreads();
    // phase D: wave-per-node register accumulation + fused exact GELU
    const int wave = threadIdx.x >> 6;
    const int lane = threadIdx.x & 63;
    for (int nr = wave; nr < NB; nr += 16) {
        const int n = (b << 6) + nr;
        if (n >= N) continue;
        const int p0 = (int)off_l[nr];
        const int p1 = p0 + (int)cnt_l[nr];
        float ax = 0.f, ay = 0.f;
        int p = p0;
        for (; p + 4 <= p1; p += 4) {     // 4 indep 256B gathers in flight
            const uint2 e0 = srec[p];
            const uint2 e1 = srec[p + 1];
            const uint2 e2 = srec[p + 2];
            const uint2 e3 = srec[p + 3];
            const unsigned u0 = mbp[(size_t)(e0.x & 0xffffffu) * 64 + lane];
            const unsigned u1 = mbp[(size_t)(e1.x & 0xffffffu) * 64 + lane];
            const unsigned u2 = mbp[(size_t)(e2.x & 0xffffffu) * 64 + lane];
            const unsigned u3 = mbp[(size_t)(e3.x & 0xffffffu) * 64 + lane];
            const float a0 = __uint_as_float(e0.y);
            const float a1 = __uint_as_float(e1.y);
            const float a2 = __uint_as_float(e2.y);
            const float a3 = __uint_as_float(e3.y);
            ax = fmaf(a0, bf_lo(u0), ax);
            ay = fmaf(a0, bf_hi(u0), ay);
            ax = fmaf(a1, bf_lo(u1), ax);
            ay = fmaf(a1, bf_hi(u1), ay);
            ax = fmaf(a2, bf_lo(u2), ax);
            ay = fmaf(a2, bf_hi(u2), ay);
            ax = fmaf(a3, bf_lo(u3), ax);
            ay = fmaf(a3, bf_hi(u3), ay);
        }
        for (; p < p1; ++p) {
            const uint2 e = srec[p];
            const unsigned u = mbp[(size_t)(e.x & 0xffffffu) * 64 + lane];
            const float a = __uint_as_float(e.y);
            ax = fmaf(a, bf_lo(u), ax);
            ay = fmaf(a, bf_hi(u), ay);
        }
        out[(size_t)n * HDIM + lane] = gelu_f(ax);
        out[(size_t)n * HDIM + 64 + lane] = gelu_f(ay);
    }
}

// ---- launcher ---------------------------------------------------------------
extern "C" void kernel_launch(void* const* d_in, const int* in_sizes, int n_in,
                              void* d_out, int out_size, void* d_ws,
                              size_t ws_size, hipStream_t stream) {
    const float* x   = (const float*)d_in[0];
    const int*   eix = (const int*)d_in[1];
    const float* a_i = (const float*)d_in[2];
    const float* a_j = (const float*)d_in[3];
    const float* Wm  = (const float*)d_in[4];
    float* out = (float*)d_out;

    const int N = in_sizes[0] / HDIM;  // 50000
    const int E = in_sizes[1] / 2;     // 800000
    const int nbuk = (N + NB - 1) / NB;  // 782

    // workspace layout (~89 MB, all sections 16B-aligned)
    unsigned* xbp  = (unsigned*)d_ws;                     // N*64 (12.8 MB)
    unsigned* mbp  = xbp + (size_t)N * 64;                // N*64 (12.8 MB)
    float* denp    = (float*)(mbp + (size_t)N * 64);      // DP*N (51.2 MB)
    float* si      = denp + (size_t)DP * N;               // N
    float* sj      = si + N;                              // N
    float* denom   = sj + N;                              // N
    unsigned* gcnt = (unsigned*)(denom + N);              // 1024
    unsigned short* exbuf = (unsigned short*)(gcnt + 1024);  // E (1.6 MB)
    uint2* edges   = (uint2*)(exbuf + E);                 // nbuk*CAP (9.6 MB)

    const int* idx_j = eix;       // edge_index[0]: output node
    const int* idx_i = eix + E;   // edge_index[1]: source / softmax segment

    k_scores<<<(N + 3) / 4, 256, 0, stream>>>(x, a_i, a_j, si, sj, xbp, gcnt,
                                              N);
    k_den<<<DP, 1024, 0, stream>>>(idx_i, idx_j, si, sj, exbuf, denp, N, E);
    k_denred<<<(N + 255) / 256, 256, 0, stream>>>(denp, denom, N);
    k_gemm<<<(N + 63) / 64, 256, 0, stream>>>(xbp, Wm, denom, mbp, N);
    k_bin<<<BINB, 1024, 0, stream>>>(idx_i, idx_j, exbuf, gcnt, edges, nbuk,
                                     E);
    k_agg<<<nbuk, 1024, 0, stream>>>(gcnt, edges, mbp, out, N);
}